// Round 1
// baseline (645.120 us; speedup 1.0000x reference)
//
#include <hip/hip_runtime.h>

#define NB 16
#define NN 512
#define NP 513   // N+1
#define NM 511   // N-1
#define CFLc 0.5f

#define SE (NP*NP)     // 263169 per-batch E
#define SHX (NM*NN)    // 261632 per-batch Hx (511 rows x 512 cols)
#define SHY (NN*NM)    // 261632 per-batch Hy (512 rows x 511 cols)

// combined local stencil g[p][q] = beta*fb + delta*fd + fy, shape (3,4), into shared
__device__ __forceinline__ void load_g(const float* beta, const float* delta,
                                       const float* fb, const float* fd, const float* fy,
                                       float* gs) {
    if (threadIdx.x < 12)
        gs[threadIdx.x] = beta[0]*fb[threadIdx.x] + delta[0]*fd[threadIdx.x] + fy[threadIdx.x];
    __syncthreads();
}

// ---------------- Amper: E_new = E + CFL*(s1 - s2) ----------------

// interior local stencil part (covers whole E; boundary cells = copy)
__global__ __launch_bounds__(256) void k_amper_local(
    const float* __restrict__ E, const float* __restrict__ Hx, const float* __restrict__ Hy,
    const float* __restrict__ beta, const float* __restrict__ delta,
    const float* __restrict__ fb, const float* __restrict__ fd, const float* __restrict__ fy,
    float* __restrict__ Eout)
{
    __shared__ float gs[12];
    load_g(beta, delta, fb, fd, fy, gs);
    int b = blockIdx.y;
    int idx = blockIdx.x*256 + threadIdx.x;
    if (idx >= SE) return;
    int r = idx / NP, c = idx - r*NP;
    float v = E[(size_t)b*SE + idx];
    if (r >= 2 && r <= 510 && c >= 2 && c <= 510) {
        const float* Hyb = Hy + (size_t)b*SHY + (size_t)(r-2)*NM + (c-2);
        const float* Hxb = Hx + (size_t)b*SHX + (size_t)(r-2)*NN + (c-2);
        float s1 = 0.f, s2 = 0.f;
        #pragma unroll
        for (int p = 0; p < 4; p++)
            #pragma unroll
            for (int q = 0; q < 3; q++) s1 += gs[q*4+p] * Hyb[p*NM + q];   // conv(Hy, g^T)
        #pragma unroll
        for (int p = 0; p < 3; p++)
            #pragma unroll
            for (int q = 0; q < 4; q++) s2 += gs[p*4+q] * Hxb[p*NN + q];   // conv(Hx, g)
        v += CFLc * (s1 - s2);
    }
    Eout[(size_t)b*SE + idx] = v;
}

// boundary columns from Hy: cols {0,1,2,510,511,512}, rows 2..510. One wave per (b, row i).
__global__ __launch_bounds__(256) void k_amper_edge_cols(
    const float* __restrict__ Hy,
    const float* __restrict__ kf, const float* __restrict__ kb,
    const float* __restrict__ fu, const float* __restrict__ fdn,
    float* __restrict__ Eout)
{
    int b = blockIdx.y;
    int lane = threadIdx.x & 63;
    int i = blockIdx.x*4 + (threadIdx.x >> 6);   // output row index 0..508 -> E row i+2
    if (i > 508) return;
    const float* Hyb = Hy + (size_t)b*SHY + (size_t)i*NM;
    const float4* kf4 = (const float4*)kf;
    const float4* kb4 = (const float4*)kb;
    const float4* fu4 = (const float4*)fu;
    const float4* fd4 = (const float4*)fdn;
    float akf0=0,akf1=0,akb0=0,akb1=0,afu0=0,afu1=0,afd0=0,afd1=0;
    for (int m = lane; m < NM; m += 64) {           // m: Hy column
        float h0 = Hyb[m], h1 = Hyb[NM+m], h2 = Hyb[2*NM+m], h3 = Hyb[3*NM+m];
        if (m <= 509) {                              // j=0 term, coef row m
            float4 c;
            c = kf4[m]; akf0 += h0*c.x + h1*c.y + h2*c.z + h3*c.w;
            c = kb4[m]; akb0 += h0*c.x + h1*c.y + h2*c.z + h3*c.w;
            c = fu4[m]; afu0 += h0*c.x + h1*c.y + h2*c.z + h3*c.w;
            c = fd4[m]; afd0 += h0*c.x + h1*c.y + h2*c.z + h3*c.w;
        }
        if (m >= 1) {                                // j=1 term, coef row m-1
            float4 c;
            c = kf4[m-1]; akf1 += h0*c.x + h1*c.y + h2*c.z + h3*c.w;
            c = kb4[m-1]; akb1 += h0*c.x + h1*c.y + h2*c.z + h3*c.w;
            c = fu4[m-1]; afu1 += h0*c.x + h1*c.y + h2*c.z + h3*c.w;
            c = fd4[m-1]; afd1 += h0*c.x + h1*c.y + h2*c.z + h3*c.w;
        }
    }
    #pragma unroll
    for (int off = 32; off > 0; off >>= 1) {
        akf0 += __shfl_down(akf0, off); akf1 += __shfl_down(akf1, off);
        akb0 += __shfl_down(akb0, off); akb1 += __shfl_down(akb1, off);
        afu0 += __shfl_down(afu0, off); afu1 += __shfl_down(afu1, off);
        afd0 += __shfl_down(afd0, off); afd1 += __shfl_down(afd1, off);
    }
    if (lane == 0) {
        float* Eo = Eout + (size_t)b*SE + (size_t)(2+i)*NP;
        Eo[0]   += CFLc * akf0;
        Eo[1]   += CFLc * (akf1 + afu0);
        Eo[2]   += CFLc * afu1;
        Eo[510] += CFLc * afd0;
        Eo[511] += CFLc * (afd1 + akb0);
        Eo[512] += CFLc * akb1;
    }
}

// boundary rows from Hx: rows {0,1,2,510,511,512}, cols 2..510. Thread per col, p-chunked.
__global__ __launch_bounds__(256) void k_amper_edge_rows(
    const float* __restrict__ Hx,
    const float* __restrict__ kf, const float* __restrict__ kb,
    const float* __restrict__ fu, const float* __restrict__ fdn,
    float* __restrict__ Eout)
{
    int b = blockIdx.z;
    int j = blockIdx.x*256 + threadIdx.x;    // 0..508 -> E col j+2
    if (j > 508) return;
    int p0 = blockIdx.y * 64;
    int p1 = min(510, p0 + 64);
    const float* Hxb = Hx + (size_t)b*SHX;
    float akf0=0,akf1=0,akb0=0,akb1=0,afu0=0,afu1=0,afd0=0,afd1=0;
    float r0[4], r1[4];
    #pragma unroll
    for (int q = 0; q < 4; q++) r0[q] = Hxb[(size_t)p0*NN + j + q];
    for (int p = p0; p < p1; p++) {
        #pragma unroll
        for (int q = 0; q < 4; q++) r1[q] = Hxb[(size_t)(p+1)*NN + j + q];
        #pragma unroll
        for (int q = 0; q < 4; q++) {
            float ckf = kf[p*4+q], ckb = kb[p*4+q], cfu = fu[p*4+q], cfd = fdn[p*4+q];
            akf0 += r0[q]*ckf; akf1 += r1[q]*ckf;
            akb0 += r0[q]*ckb; akb1 += r1[q]*ckb;
            afu0 += r0[q]*cfu; afu1 += r1[q]*cfu;
            afd0 += r0[q]*cfd; afd1 += r1[q]*cfd;
        }
        #pragma unroll
        for (int q = 0; q < 4; q++) r0[q] = r1[q];
    }
    float* Eb = Eout + (size_t)b*SE;
    int c = 2 + j;
    atomicAdd(&Eb[0*NP   + c], -CFLc * akf0);
    atomicAdd(&Eb[1*NP   + c], -CFLc * (akf1 + afu0));
    atomicAdd(&Eb[2*NP   + c], -CFLc * afu1);
    atomicAdd(&Eb[510*NP + c], -CFLc * afd0);
    atomicAdd(&Eb[511*NP + c], -CFLc * (afd1 + akb0));
    atomicAdd(&Eb[512*NP + c], -CFLc * akb1);
}

// ---------------- Faraday: Hx_new = Hx - CFL*s3 ; Hy_new = Hy + CFL*s4 ----------------

__global__ __launch_bounds__(256) void k_faraday_hx_local(
    const float* __restrict__ E, const float* __restrict__ Hx,
    const float* __restrict__ beta, const float* __restrict__ delta,
    const float* __restrict__ fb, const float* __restrict__ fd, const float* __restrict__ fy,
    float* __restrict__ Hxout)
{
    __shared__ float gs[12];
    load_g(beta, delta, fb, fd, fy, gs);
    int b = blockIdx.y;
    int idx = blockIdx.x*256 + threadIdx.x;
    if (idx >= SHX) return;
    int r = idx / NN, c = idx - r*NN;    // r 0..510, c 0..511
    float v = Hx[(size_t)b*SHX + idx];
    if (c >= 1 && c <= 510) {
        const float* Eb = E + (size_t)b*SE + (size_t)r*NP + (c-1);
        float s = 0.f;
        #pragma unroll
        for (int p = 0; p < 3; p++)
            #pragma unroll
            for (int q = 0; q < 4; q++) s += gs[p*4+q] * Eb[p*NP + q];
        v -= CFLc * s;
    }
    Hxout[(size_t)b*SHX + idx] = v;
}

// Hx boundary cols {0,1,510,511}, all rows. One wave per (b, r).
__global__ __launch_bounds__(256) void k_faraday_hx_edge(
    const float* __restrict__ E,
    const float* __restrict__ kef, const float* __restrict__ keb,
    float* __restrict__ Hxout)
{
    int b = blockIdx.y;
    int lane = threadIdx.x & 63;
    int r = blockIdx.x*4 + (threadIdx.x >> 6);   // 0..510
    if (r > 510) return;
    const float* Eb = E + (size_t)b*SE + (size_t)r*NP;
    float af0=0, af1=0, ab0=0, ab1=0;
    for (int m = lane; m < NP; m += 64) {
        float e0 = Eb[m], e1 = Eb[NP+m], e2 = Eb[2*NP+m];
        if (m <= 511) {
            af0 += e0*kef[m] + e1*kef[512+m] + e2*kef[1024+m];
            ab0 += e0*keb[m] + e1*keb[512+m] + e2*keb[1024+m];
        }
        if (m >= 1) {
            af1 += e0*kef[m-1] + e1*kef[512+m-1] + e2*kef[1024+m-1];
            ab1 += e0*keb[m-1] + e1*keb[512+m-1] + e2*keb[1024+m-1];
        }
    }
    #pragma unroll
    for (int off = 32; off > 0; off >>= 1) {
        af0 += __shfl_down(af0, off); af1 += __shfl_down(af1, off);
        ab0 += __shfl_down(ab0, off); ab1 += __shfl_down(ab1, off);
    }
    if (lane == 0) {
        float* Ho = Hxout + (size_t)b*SHX + (size_t)r*NN;
        Ho[0]   -= CFLc * af0;
        Ho[1]   -= CFLc * af1;
        Ho[510] -= CFLc * ab0;
        Ho[511] -= CFLc * ab1;
    }
}

__global__ __launch_bounds__(256) void k_faraday_hy_local(
    const float* __restrict__ E, const float* __restrict__ Hy,
    const float* __restrict__ beta, const float* __restrict__ delta,
    const float* __restrict__ fb, const float* __restrict__ fd, const float* __restrict__ fy,
    float* __restrict__ Hyout)
{
    __shared__ float gs[12];
    load_g(beta, delta, fb, fd, fy, gs);
    int b = blockIdx.y;
    int idx = blockIdx.x*256 + threadIdx.x;
    if (idx >= SHY) return;
    int r = idx / NM, c = idx - r*NM;    // r 0..511, c 0..510
    float v = Hy[(size_t)b*SHY + idx];
    if (r >= 1 && r <= 510) {
        const float* Eb = E + (size_t)b*SE + (size_t)(r-1)*NP + c;
        float s = 0.f;
        #pragma unroll
        for (int p = 0; p < 4; p++)
            #pragma unroll
            for (int q = 0; q < 3; q++) s += gs[q*4+p] * Eb[p*NP + q];
        v += CFLc * s;
    }
    Hyout[(size_t)b*SHY + idx] = v;
}

// Hy boundary rows {0,1,510,511}, all cols. Thread per col, p-chunked.
__global__ __launch_bounds__(256) void k_faraday_hy_edge(
    const float* __restrict__ E,
    const float* __restrict__ kef, const float* __restrict__ keb,
    float* __restrict__ Hyout)
{
    int b = blockIdx.z;
    int c = blockIdx.x*256 + threadIdx.x;   // 0..510
    if (c > 510) return;
    int p0 = blockIdx.y * 64, p1 = p0 + 64;  // p in 0..511, 8 exact chunks
    const float* Eb = E + (size_t)b*SE;
    float af0=0, af1=0, ab0=0, ab1=0;
    float r0[3], r1[3];
    #pragma unroll
    for (int q = 0; q < 3; q++) r0[q] = Eb[(size_t)p0*NP + c + q];
    for (int p = p0; p < p1; p++) {
        #pragma unroll
        for (int q = 0; q < 3; q++) r1[q] = Eb[(size_t)(p+1)*NP + c + q];
        float cf0 = kef[p], cf1 = kef[512+p], cf2 = kef[1024+p];   // kef[q*512+p]
        float cb0 = keb[p], cb1 = keb[512+p], cb2 = keb[1024+p];
        af0 += r0[0]*cf0 + r0[1]*cf1 + r0[2]*cf2;
        af1 += r1[0]*cf0 + r1[1]*cf1 + r1[2]*cf2;
        ab0 += r0[0]*cb0 + r0[1]*cb1 + r0[2]*cb2;
        ab1 += r1[0]*cb0 + r1[1]*cb1 + r1[2]*cb2;
        r0[0]=r1[0]; r0[1]=r1[1]; r0[2]=r1[2];
    }
    float* Ho = Hyout + (size_t)b*SHY;
    atomicAdd(&Ho[0*NM   + c], CFLc * af0);
    atomicAdd(&Ho[1*NM   + c], CFLc * af1);
    atomicAdd(&Ho[510*NM + c], CFLc * ab0);
    atomicAdd(&Ho[511*NM + c], CFLc * ab1);
}

// ---------------- driver ----------------

static void run_step(const float* Ein, const float* Hxin, const float* Hyin,
                     float* Eout, float* Hxout, float* Hyout,
                     const float* beta, const float* delta,
                     const float* fb, const float* fd, const float* fy,
                     const float* kf, const float* kb, const float* fu, const float* fdn,
                     const float* kef, const float* keb, hipStream_t stream)
{
    dim3 blk(256);
    k_amper_local<<<dim3((SE+255)/256, NB), blk, 0, stream>>>(Ein, Hxin, Hyin, beta, delta, fb, fd, fy, Eout);
    k_amper_edge_cols<<<dim3(128, NB), blk, 0, stream>>>(Hyin, kf, kb, fu, fdn, Eout);
    k_amper_edge_rows<<<dim3(2, 8, NB), blk, 0, stream>>>(Hxin, kf, kb, fu, fdn, Eout);
    k_faraday_hx_local<<<dim3((SHX+255)/256, NB), blk, 0, stream>>>(Eout, Hxin, beta, delta, fb, fd, fy, Hxout);
    k_faraday_hx_edge<<<dim3(128, NB), blk, 0, stream>>>(Eout, kef, keb, Hxout);
    k_faraday_hy_local<<<dim3((SHY+255)/256, NB), blk, 0, stream>>>(Eout, Hyin, beta, delta, fb, fd, fy, Hyout);
    k_faraday_hy_edge<<<dim3(2, 8, NB), blk, 0, stream>>>(Eout, kef, keb, Hyout);
}

extern "C" void kernel_launch(void* const* d_in, const int* in_sizes, int n_in,
                              void* d_out, int out_size, void* d_ws, size_t ws_size,
                              hipStream_t stream)
{
    const float* E1   = (const float*)d_in[0];
    const float* Hx1  = (const float*)d_in[1];
    const float* Hy1  = (const float*)d_in[2];
    const float* beta = (const float*)d_in[9];
    const float* delta= (const float*)d_in[10];
    const float* fb   = (const float*)d_in[11];
    const float* fd   = (const float*)d_in[12];
    const float* fy   = (const float*)d_in[13];
    const float* kf   = (const float*)d_in[14];
    const float* kb   = (const float*)d_in[15];
    const float* fu   = (const float*)d_in[16];
    const float* fdn  = (const float*)d_in[17];
    const float* kef  = (const float*)d_in[18];
    const float* keb  = (const float*)d_in[19];

    float* out = (float*)d_out;
    size_t SEa = (size_t)NB * SE;
    size_t SHa = (size_t)NB * SHX;   // == NB*SHY
    float* E2  = out;
    float* Hx2 = E2  + SEa;
    float* Hy2 = Hx2 + SHa;
    float* E3  = Hy2 + SHa;
    float* Hx3 = E3  + SEa;
    float* Hy3 = Hx3 + SHa;
    float* E4  = Hy3 + SHa;
    float* Hx4 = E4  + SEa;
    float* Hy4 = Hx4 + SHa;

    run_step(E1, Hx1, Hy1, E2, Hx2, Hy2, beta, delta, fb, fd, fy, kf, kb, fu, fdn, kef, keb, stream);
    run_step(E2, Hx2, Hy2, E3, Hx3, Hy3, beta, delta, fb, fd, fy, kf, kb, fu, fdn, kef, keb, stream);
    run_step(E3, Hx3, Hy3, E4, Hx4, Hy4, beta, delta, fb, fd, fy, kf, kb, fu, fdn, kef, keb, stream);
}

// Round 2
// 616.487 us; speedup vs baseline: 1.0464x; 1.0464x over previous
//
#include <hip/hip_runtime.h>

#define NB 16
#define NN 512
#define NP 513   // N+1
#define NM 511   // N-1
#define CFLc 0.5f

#define SE (NP*NP)     // 263169 per-batch E
#define SHX (NM*NN)    // 261632 per-batch Hx (511 rows x 512 cols)
#define SHY (NN*NM)    // 261632 per-batch Hy (512 rows x 511 cols)

// scratch layout (floats), reused across the 3 steps (stream-serialized):
//  ws_ar [16][8][6][512]  amper row-edge partials (from Hx), chunked over p
//  ws_ac [16][512][6]     amper col-edge combined (from Hy), per output row i
//  ws_fx [16][512][4]     faraday hx-edge combined, per row r
//  ws_fy [16][8][4][512]  faraday hy-edge partials, chunked over p
#define WS_AR 0
#define WS_AC (WS_AR + 16*8*6*512)
#define WS_FX (WS_AC + 16*512*6)
#define WS_FY (WS_FX + 16*512*4)
#define WS_TOT (WS_FY + 16*8*4*512)   // 737280 floats = 2.95 MB

__device__ __forceinline__ void load_g(const float* beta, const float* delta,
                                       const float* fb, const float* fd, const float* fy,
                                       float* gs) {
    if (threadIdx.x < 12)
        gs[threadIdx.x] = beta[0]*fb[threadIdx.x] + delta[0]*fd[threadIdx.x] + fy[threadIdx.x];
    __syncthreads();
}

// ============ Amper edges -> scratch (reads Hx, Hy only) ============
__global__ __launch_bounds__(256) void k_amper_edges(
    const float* __restrict__ Hx, const float* __restrict__ Hy,
    const float* __restrict__ kf, const float* __restrict__ kb,
    const float* __restrict__ fu, const float* __restrict__ fdn,
    float* __restrict__ ws)
{
    int id = blockIdx.x;
    if (id < 2048) {
        // part A: col edges from Hy. one wave per (b, output row i)
        int b = id >> 7;          // 0..15
        int g = id & 127;         // 0..127
        int lane = threadIdx.x & 63;
        int i = g*4 + (threadIdx.x >> 6);   // 0..508
        if (i > 508) return;
        const float* Hyb = Hy + (size_t)b*SHY + (size_t)i*NM;
        const float4* kf4 = (const float4*)kf;
        const float4* kb4 = (const float4*)kb;
        const float4* fu4 = (const float4*)fu;
        const float4* fd4 = (const float4*)fdn;
        float akf0=0,akf1=0,akb0=0,akb1=0,afu0=0,afu1=0,afd0=0,afd1=0;
        for (int m = lane; m < NM; m += 64) {
            float h0 = Hyb[m], h1 = Hyb[NM+m], h2 = Hyb[2*NM+m], h3 = Hyb[3*NM+m];
            if (m <= 509) {
                float4 c;
                c = kf4[m]; akf0 += h0*c.x + h1*c.y + h2*c.z + h3*c.w;
                c = kb4[m]; akb0 += h0*c.x + h1*c.y + h2*c.z + h3*c.w;
                c = fu4[m]; afu0 += h0*c.x + h1*c.y + h2*c.z + h3*c.w;
                c = fd4[m]; afd0 += h0*c.x + h1*c.y + h2*c.z + h3*c.w;
            }
            if (m >= 1) {
                float4 c;
                c = kf4[m-1]; akf1 += h0*c.x + h1*c.y + h2*c.z + h3*c.w;
                c = kb4[m-1]; akb1 += h0*c.x + h1*c.y + h2*c.z + h3*c.w;
                c = fu4[m-1]; afu1 += h0*c.x + h1*c.y + h2*c.z + h3*c.w;
                c = fd4[m-1]; afd1 += h0*c.x + h1*c.y + h2*c.z + h3*c.w;
            }
        }
        #pragma unroll
        for (int off = 32; off > 0; off >>= 1) {
            akf0 += __shfl_down(akf0, off); akf1 += __shfl_down(akf1, off);
            akb0 += __shfl_down(akb0, off); akb1 += __shfl_down(akb1, off);
            afu0 += __shfl_down(afu0, off); afu1 += __shfl_down(afu1, off);
            afd0 += __shfl_down(afd0, off); afd1 += __shfl_down(afd1, off);
        }
        if (lane == 0) {
            float* o = ws + WS_AC + ((size_t)b*512 + i)*6;
            o[0] = akf0;
            o[1] = akf1 + afu0;
            o[2] = afu1;
            o[3] = afd0;
            o[4] = afd1 + akb0;
            o[5] = akb1;
        }
    } else {
        // part B: row edges from Hx. thread per col j, p-chunked x8
        int t = id - 2048;        // 0..255
        int b = t >> 4;
        int rem = t & 15;
        int chunk = rem >> 1;
        int j = (rem & 1)*256 + threadIdx.x;   // 0..508
        if (j > 508) return;
        int p0 = chunk * 64;
        int p1 = min(510, p0 + 64);
        const float* Hxb = Hx + (size_t)b*SHX;
        float akf0=0,akf1=0,akb0=0,akb1=0,afu0=0,afu1=0,afd0=0,afd1=0;
        float r0[4], r1[4];
        #pragma unroll
        for (int q = 0; q < 4; q++) r0[q] = Hxb[(size_t)p0*NN + j + q];
        for (int p = p0; p < p1; p++) {
            #pragma unroll
            for (int q = 0; q < 4; q++) r1[q] = Hxb[(size_t)(p+1)*NN + j + q];
            #pragma unroll
            for (int q = 0; q < 4; q++) {
                float ckf = kf[p*4+q], ckb = kb[p*4+q], cfu = fu[p*4+q], cfd = fdn[p*4+q];
                akf0 += r0[q]*ckf; akf1 += r1[q]*ckf;
                akb0 += r0[q]*ckb; akb1 += r1[q]*ckb;
                afu0 += r0[q]*cfu; afu1 += r1[q]*cfu;
                afd0 += r0[q]*cfd; afd1 += r1[q]*cfd;
            }
            #pragma unroll
            for (int q = 0; q < 4; q++) r0[q] = r1[q];
        }
        float* o = ws + WS_AR + (((size_t)b*8 + chunk)*6)*512 + j;
        o[0*512] = akf0;
        o[1*512] = akf1 + afu0;
        o[2*512] = afu1;
        o[3*512] = afd0;
        o[4*512] = afd1 + akb0;
        o[5*512] = akb1;
    }
}

// ============ Amper local: writes COMPLETE E_out (interior + boundary) ============
__global__ __launch_bounds__(256) void k_amper_local(
    const float* __restrict__ E, const float* __restrict__ Hx, const float* __restrict__ Hy,
    const float* __restrict__ beta, const float* __restrict__ delta,
    const float* __restrict__ fb, const float* __restrict__ fd, const float* __restrict__ fy,
    const float* __restrict__ ws,
    float* __restrict__ Eout)
{
    __shared__ float gs[12];
    load_g(beta, delta, fb, fd, fy, gs);
    int b = blockIdx.y;
    int idx = blockIdx.x*256 + threadIdx.x;
    if (idx >= SE) return;
    int r = idx / NP, c = idx - r*NP;
    float v = E[(size_t)b*SE + idx];
    bool rint = (r >= 2 && r <= 510);
    bool cint = (c >= 2 && c <= 510);
    if (rint && cint) {
        const float* Hyb = Hy + (size_t)b*SHY + (size_t)(r-2)*NM + (c-2);
        const float* Hxb = Hx + (size_t)b*SHX + (size_t)(r-2)*NN + (c-2);
        float s1 = 0.f, s2 = 0.f;
        #pragma unroll
        for (int p = 0; p < 4; p++)
            #pragma unroll
            for (int q = 0; q < 3; q++) s1 += gs[q*4+p] * Hyb[p*NM + q];
        #pragma unroll
        for (int p = 0; p < 3; p++)
            #pragma unroll
            for (int q = 0; q < 4; q++) s2 += gs[p*4+q] * Hxb[p*NN + q];
        v += CFLc * (s1 - s2);
    }
    if (rint) {
        // col-edge contributions (from Hy), cols {0,1,2,510,511,512}
        int slot = -1;
        if (c == 0) slot = 0; else if (c == 1) slot = 1; else if (c == 2) slot = 2;
        else if (c == 510) slot = 3; else if (c == 511) slot = 4; else if (c == 512) slot = 5;
        if (slot >= 0)
            v += CFLc * ws[WS_AC + ((size_t)b*512 + (r-2))*6 + slot];
    }
    if (cint) {
        // row-edge contributions (from Hx), rows {0,1,2,510,511,512}
        int rs = -1;
        if (r == 0) rs = 0; else if (r == 1) rs = 1; else if (r == 2) rs = 2;
        else if (r == 510) rs = 3; else if (r == 511) rs = 4; else if (r == 512) rs = 5;
        if (rs >= 0) {
            float s = 0.f;
            #pragma unroll
            for (int ch = 0; ch < 8; ch++)
                s += ws[WS_AR + (((size_t)b*8 + ch)*6 + rs)*512 + (c-2)];
            v -= CFLc * s;
        }
    }
    Eout[(size_t)b*SE + idx] = v;
}

// ============ Faraday edges -> scratch (reads E only) ============
__global__ __launch_bounds__(256) void k_faraday_edges(
    const float* __restrict__ E,
    const float* __restrict__ kef, const float* __restrict__ keb,
    float* __restrict__ ws)
{
    int id = blockIdx.x;
    if (id < 2048) {
        // hx edge: one wave per (b, r)
        int b = id >> 7;
        int g = id & 127;
        int lane = threadIdx.x & 63;
        int r = g*4 + (threadIdx.x >> 6);   // 0..510
        if (r > 510) return;
        const float* Eb = E + (size_t)b*SE + (size_t)r*NP;
        float af0=0, af1=0, ab0=0, ab1=0;
        for (int m = lane; m < NP; m += 64) {
            float e0 = Eb[m], e1 = Eb[NP+m], e2 = Eb[2*NP+m];
            if (m <= 511) {
                af0 += e0*kef[m] + e1*kef[512+m] + e2*kef[1024+m];
                ab0 += e0*keb[m] + e1*keb[512+m] + e2*keb[1024+m];
            }
            if (m >= 1) {
                af1 += e0*kef[m-1] + e1*kef[512+m-1] + e2*kef[1024+m-1];
                ab1 += e0*keb[m-1] + e1*keb[512+m-1] + e2*keb[1024+m-1];
            }
        }
        #pragma unroll
        for (int off = 32; off > 0; off >>= 1) {
            af0 += __shfl_down(af0, off); af1 += __shfl_down(af1, off);
            ab0 += __shfl_down(ab0, off); ab1 += __shfl_down(ab1, off);
        }
        if (lane == 0) {
            float* o = ws + WS_FX + ((size_t)b*512 + r)*4;
            o[0] = af0; o[1] = af1; o[2] = ab0; o[3] = ab1;
        }
    } else {
        // hy edge: thread per col c, p-chunked x8
        int t = id - 2048;
        int b = t >> 4;
        int rem = t & 15;
        int chunk = rem >> 1;
        int c = (rem & 1)*256 + threadIdx.x;   // 0..510
        if (c > 510) return;
        int p0 = chunk*64, p1 = p0 + 64;
        const float* Eb = E + (size_t)b*SE;
        float af0=0, af1=0, ab0=0, ab1=0;
        float r0[3], r1[3];
        #pragma unroll
        for (int q = 0; q < 3; q++) r0[q] = Eb[(size_t)p0*NP + c + q];
        for (int p = p0; p < p1; p++) {
            #pragma unroll
            for (int q = 0; q < 3; q++) r1[q] = Eb[(size_t)(p+1)*NP + c + q];
            float cf0 = kef[p], cf1 = kef[512+p], cf2 = kef[1024+p];
            float cb0 = keb[p], cb1 = keb[512+p], cb2 = keb[1024+p];
            af0 += r0[0]*cf0 + r0[1]*cf1 + r0[2]*cf2;
            af1 += r1[0]*cf0 + r1[1]*cf1 + r1[2]*cf2;
            ab0 += r0[0]*cb0 + r0[1]*cb1 + r0[2]*cb2;
            ab1 += r1[0]*cb0 + r1[1]*cb1 + r1[2]*cb2;
            r0[0]=r1[0]; r0[1]=r1[1]; r0[2]=r1[2];
        }
        float* o = ws + WS_FY + (((size_t)b*8 + chunk)*4)*512 + c;
        o[0*512] = af0; o[1*512] = af1; o[2*512] = ab0; o[3*512] = ab1;
    }
}

// ============ Faraday local: writes COMPLETE Hx_out and Hy_out ============
__global__ __launch_bounds__(256) void k_faraday_local(
    const float* __restrict__ E, const float* __restrict__ Hx, const float* __restrict__ Hy,
    const float* __restrict__ beta, const float* __restrict__ delta,
    const float* __restrict__ fb, const float* __restrict__ fd, const float* __restrict__ fy,
    const float* __restrict__ ws,
    float* __restrict__ Hxout, float* __restrict__ Hyout)
{
    __shared__ float gs[12];
    load_g(beta, delta, fb, fd, fy, gs);
    int b = blockIdx.y;
    int idx = blockIdx.x*256 + threadIdx.x;
    if (idx < SHX) {
        int r = idx / NN, c = idx - r*NN;    // r 0..510, c 0..511
        float v = Hx[(size_t)b*SHX + idx];
        if (c >= 1 && c <= 510) {
            const float* Eb = E + (size_t)b*SE + (size_t)r*NP + (c-1);
            float s = 0.f;
            #pragma unroll
            for (int p = 0; p < 3; p++)
                #pragma unroll
                for (int q = 0; q < 4; q++) s += gs[p*4+q] * Eb[p*NP + q];
            v -= CFLc * s;
        }
        int slot = -1;
        if (c == 0) slot = 0; else if (c == 1) slot = 1;
        else if (c == 510) slot = 2; else if (c == 511) slot = 3;
        if (slot >= 0)
            v -= CFLc * ws[WS_FX + ((size_t)b*512 + r)*4 + slot];
        Hxout[(size_t)b*SHX + idx] = v;
    } else {
        int j = idx - SHX;
        if (j >= SHY) return;
        int r = j / NM, c = j - r*NM;        // r 0..511, c 0..510
        float v = Hy[(size_t)b*SHY + j];
        if (r >= 1 && r <= 510) {
            const float* Eb = E + (size_t)b*SE + (size_t)(r-1)*NP + c;
            float s = 0.f;
            #pragma unroll
            for (int p = 0; p < 4; p++)
                #pragma unroll
                for (int q = 0; q < 3; q++) s += gs[q*4+p] * Eb[p*NP + q];
            v += CFLc * s;
        }
        int rs = -1;
        if (r == 0) rs = 0; else if (r == 1) rs = 1;
        else if (r == 510) rs = 2; else if (r == 511) rs = 3;
        if (rs >= 0) {
            float s = 0.f;
            #pragma unroll
            for (int ch = 0; ch < 8; ch++)
                s += ws[WS_FY + (((size_t)b*8 + ch)*4 + rs)*512 + c];
            v += CFLc * s;
        }
        Hyout[(size_t)b*SHY + j] = v;
    }
}

// ---------------- driver ----------------

static void run_step(const float* Ein, const float* Hxin, const float* Hyin,
                     float* Eout, float* Hxout, float* Hyout, float* ws,
                     const float* beta, const float* delta,
                     const float* fb, const float* fd, const float* fy,
                     const float* kf, const float* kb, const float* fu, const float* fdn,
                     const float* kef, const float* keb, hipStream_t stream)
{
    dim3 blk(256);
    k_amper_edges<<<dim3(2304), blk, 0, stream>>>(Hxin, Hyin, kf, kb, fu, fdn, ws);
    k_amper_local<<<dim3((SE+255)/256, NB), blk, 0, stream>>>(Ein, Hxin, Hyin, beta, delta, fb, fd, fy, ws, Eout);
    k_faraday_edges<<<dim3(2304), blk, 0, stream>>>(Eout, kef, keb, ws);
    k_faraday_local<<<dim3((SHX+SHY+255)/256, NB), blk, 0, stream>>>(Eout, Hxin, Hyin, beta, delta, fb, fd, fy, ws, Hxout, Hyout);
}

extern "C" void kernel_launch(void* const* d_in, const int* in_sizes, int n_in,
                              void* d_out, int out_size, void* d_ws, size_t ws_size,
                              hipStream_t stream)
{
    const float* E1   = (const float*)d_in[0];
    const float* Hx1  = (const float*)d_in[1];
    const float* Hy1  = (const float*)d_in[2];
    const float* beta = (const float*)d_in[9];
    const float* delta= (const float*)d_in[10];
    const float* fb   = (const float*)d_in[11];
    const float* fd   = (const float*)d_in[12];
    const float* fy   = (const float*)d_in[13];
    const float* kf   = (const float*)d_in[14];
    const float* kb   = (const float*)d_in[15];
    const float* fu   = (const float*)d_in[16];
    const float* fdn  = (const float*)d_in[17];
    const float* kef  = (const float*)d_in[18];
    const float* keb  = (const float*)d_in[19];

    float* out = (float*)d_out;
    float* ws  = (float*)d_ws;   // needs WS_TOT*4 = ~2.95 MB
    size_t SEa = (size_t)NB * SE;
    size_t SHa = (size_t)NB * SHX;   // == NB*SHY
    float* E2  = out;
    float* Hx2 = E2  + SEa;
    float* Hy2 = Hx2 + SHa;
    float* E3  = Hy2 + SHa;
    float* Hx3 = E3  + SEa;
    float* Hy3 = Hx3 + SHa;
    float* E4  = Hy3 + SHa;
    float* Hx4 = E4  + SEa;
    float* Hy4 = Hx4 + SHa;

    run_step(E1, Hx1, Hy1, E2, Hx2, Hy2, ws, beta, delta, fb, fd, fy, kf, kb, fu, fdn, kef, keb, stream);
    run_step(E2, Hx2, Hy2, E3, Hx3, Hy3, ws, beta, delta, fb, fd, fy, kf, kb, fu, fdn, kef, keb, stream);
    run_step(E3, Hx3, Hy3, E4, Hx4, Hy4, ws, beta, delta, fb, fd, fy, kf, kb, fu, fdn, kef, keb, stream);
}

// Round 3
// 506.090 us; speedup vs baseline: 1.2747x; 1.2181x over previous
//
#include <hip/hip_runtime.h>

#define NB 16
#define NN 512
#define NP 513   // N+1
#define NM 511   // N-1
#define CFLc 0.5f

#define SE (NP*NP)     // 263169 per-batch E
#define SHX (NM*NN)    // 261632 per-batch Hx (511 rows x 512 cols)
#define SHY (NN*NM)    // 261632 per-batch Hy (512 rows x 511 cols)

// scratch (floats). BIG region alternates amper-row partials / faraday-hy partials;
// SMALL region alternates amper-col combined / faraday-hx combined.
//  AR [16][16][6][512]  (amper row-edge partials, 16 p-chunks)   = 786432
//  FY [16][16][4][512]  (faraday hy-edge partials, 16 p-chunks)  = 524288 (fits in BIG)
//  AC [16][512][6]                                               = 49152
//  FX [16][512][4]                                               = 32768 (fits in SMALL)
#define WS_BIG 0
#define WS_SMALL (16*16*6*512)
#define WS_TOT (WS_SMALL + 16*512*6)   // 835584 floats = 3.34 MB

__device__ __forceinline__ void load_g(const float* beta, const float* delta,
                                       const float* fb, const float* fd, const float* fy,
                                       float* gs) {
    if (threadIdx.x < 12)
        gs[threadIdx.x] = beta[0]*fb[threadIdx.x] + delta[0]*fd[threadIdx.x] + fy[threadIdx.x];
    __syncthreads();
}

// ============ Amper edges -> scratch (reads Hx, Hy only) ============
__global__ __launch_bounds__(256) void k_amper_edges(
    const float* __restrict__ Hx, const float* __restrict__ Hy,
    const float* __restrict__ kf, const float* __restrict__ kb,
    const float* __restrict__ fu, const float* __restrict__ fdn,
    float* __restrict__ ws)
{
    int id = blockIdx.x;
    if (id < 2048) {
        // part A: col edges from Hy. one wave per (b, output row i)
        int b = id >> 7;
        int g = id & 127;
        int lane = threadIdx.x & 63;
        int i = g*4 + (threadIdx.x >> 6);   // 0..508
        if (i > 508) return;
        const float* Hyb = Hy + (size_t)b*SHY + (size_t)i*NM;
        const float4* kf4 = (const float4*)kf;
        const float4* kb4 = (const float4*)kb;
        const float4* fu4 = (const float4*)fu;
        const float4* fd4 = (const float4*)fdn;
        float akf0=0,akf1=0,akb0=0,akb1=0,afu0=0,afu1=0,afd0=0,afd1=0;
        for (int m = lane; m < NM; m += 64) {
            float h0 = Hyb[m], h1 = Hyb[NM+m], h2 = Hyb[2*NM+m], h3 = Hyb[3*NM+m];
            if (m <= 509) {
                float4 c;
                c = kf4[m]; akf0 += h0*c.x + h1*c.y + h2*c.z + h3*c.w;
                c = kb4[m]; akb0 += h0*c.x + h1*c.y + h2*c.z + h3*c.w;
                c = fu4[m]; afu0 += h0*c.x + h1*c.y + h2*c.z + h3*c.w;
                c = fd4[m]; afd0 += h0*c.x + h1*c.y + h2*c.z + h3*c.w;
            }
            if (m >= 1) {
                float4 c;
                c = kf4[m-1]; akf1 += h0*c.x + h1*c.y + h2*c.z + h3*c.w;
                c = kb4[m-1]; akb1 += h0*c.x + h1*c.y + h2*c.z + h3*c.w;
                c = fu4[m-1]; afu1 += h0*c.x + h1*c.y + h2*c.z + h3*c.w;
                c = fd4[m-1]; afd1 += h0*c.x + h1*c.y + h2*c.z + h3*c.w;
            }
        }
        #pragma unroll
        for (int off = 32; off > 0; off >>= 1) {
            akf0 += __shfl_down(akf0, off); akf1 += __shfl_down(akf1, off);
            akb0 += __shfl_down(akb0, off); akb1 += __shfl_down(akb1, off);
            afu0 += __shfl_down(afu0, off); afu1 += __shfl_down(afu1, off);
            afd0 += __shfl_down(afd0, off); afd1 += __shfl_down(afd1, off);
        }
        if (lane == 0) {
            float* o = ws + WS_SMALL + ((size_t)b*512 + i)*6;
            o[0] = akf0;
            o[1] = akf1 + afu0;
            o[2] = afu1;
            o[3] = afd0;
            o[4] = afd1 + akb0;
            o[5] = akb1;
        }
    } else {
        // part B: row edges from Hx. thread per col j, 16 p-chunks of 32 rows
        int t = id - 2048;        // 0..511
        int b = t >> 5;
        int rem = t & 31;
        int chunk = rem >> 1;     // 0..15
        int j = (rem & 1)*256 + threadIdx.x;   // 0..508
        if (j > 508) return;
        int p0 = chunk * 32;
        int p1 = min(510, p0 + 32);
        const float* Hxb = Hx + (size_t)b*SHX;
        float akf0=0,akf1=0,akb0=0,akb1=0,afu0=0,afu1=0,afd0=0,afd1=0;
        float r0[4], r1[4];
        #pragma unroll
        for (int q = 0; q < 4; q++) r0[q] = Hxb[(size_t)p0*NN + j + q];
        for (int p = p0; p < p1; p++) {
            #pragma unroll
            for (int q = 0; q < 4; q++) r1[q] = Hxb[(size_t)(p+1)*NN + j + q];
            #pragma unroll
            for (int q = 0; q < 4; q++) {
                float ckf = kf[p*4+q], ckb = kb[p*4+q], cfu = fu[p*4+q], cfd = fdn[p*4+q];
                akf0 += r0[q]*ckf; akf1 += r1[q]*ckf;
                akb0 += r0[q]*ckb; akb1 += r1[q]*ckb;
                afu0 += r0[q]*cfu; afu1 += r1[q]*cfu;
                afd0 += r0[q]*cfd; afd1 += r1[q]*cfd;
            }
            #pragma unroll
            for (int q = 0; q < 4; q++) r0[q] = r1[q];
        }
        float* o = ws + WS_BIG + (((size_t)b*16 + chunk)*6)*512 + j;
        o[0*512] = akf0;
        o[1*512] = akf1 + afu0;
        o[2*512] = afu1;
        o[3*512] = afd0;
        o[4*512] = afd1 + akb0;
        o[5*512] = akb1;
    }
}

// ============ Amper local: 4-row blocking, writes COMPLETE E_out ============
__global__ __launch_bounds__(256) void k_amper_local(
    const float* __restrict__ E, const float* __restrict__ Hx, const float* __restrict__ Hy,
    const float* __restrict__ beta, const float* __restrict__ delta,
    const float* __restrict__ fb, const float* __restrict__ fd, const float* __restrict__ fy,
    const float* __restrict__ ws,
    float* __restrict__ Eout)
{
    __shared__ float gs[12];
    load_g(beta, delta, fb, fd, fy, gs);
    int b = blockIdx.z;
    int c = blockIdx.x*256 + threadIdx.x;
    if (c > 512) return;
    int r0 = blockIdx.y*4;   // rows r0..r0+3 (clamped to 512)

    const float* Eb  = E  + (size_t)b*SE;
    const float* Hxb = Hx + (size_t)b*SHX;
    const float* Hyb = Hy + (size_t)b*SHY;

    // clamped column offsets (clamped values only feed non-interior outputs)
    int cy0 = min(max(c-2,0),510), cy1 = min(max(c-1,0),510), cy2 = min(c,510);
    int cx0 = max(c-2,0), cx1 = max(c-1,0), cx2 = min(c,511), cx3 = min(c+1,511);

    float hy[7][3];
    #pragma unroll
    for (int k = 0; k < 7; k++) {
        int rm = min(max(r0-2+k,0),511);
        const float* p = Hyb + (size_t)rm*NM;
        hy[k][0] = p[cy0]; hy[k][1] = p[cy1]; hy[k][2] = p[cy2];
    }
    float hx[6][4];
    #pragma unroll
    for (int k = 0; k < 6; k++) {
        int rm = min(max(r0-2+k,0),510);
        const float* p = Hxb + (size_t)rm*NN;
        hx[k][0] = p[cx0]; hx[k][1] = p[cx1]; hx[k][2] = p[cx2]; hx[k][3] = p[cx3];
    }
    float ev[4];
    #pragma unroll
    for (int j = 0; j < 4; j++)
        ev[j] = Eb[(size_t)min(r0+j,512)*NP + c];

    bool cint = (c >= 2 && c <= 510);
    int cslot = (c==0)?0:(c==1)?1:(c==2)?2:(c==510)?3:(c==511)?4:(c==512)?5:-1;

    #pragma unroll
    for (int j = 0; j < 4; j++) {
        int r = r0 + j;
        if (r > 512) break;            // wave-uniform
        float v = ev[j];
        bool rint = (r >= 2 && r <= 510);
        if (rint && cint) {
            float s1 = 0.f, s2 = 0.f;
            #pragma unroll
            for (int p = 0; p < 4; p++)
                #pragma unroll
                for (int q = 0; q < 3; q++) s1 += gs[q*4+p] * hy[j+p][q];
            #pragma unroll
            for (int p = 0; p < 3; p++)
                #pragma unroll
                for (int q = 0; q < 4; q++) s2 += gs[p*4+q] * hx[j+p][q];
            v += CFLc * (s1 - s2);
        }
        if (rint && cslot >= 0)
            v += CFLc * ws[WS_SMALL + ((size_t)b*512 + (r-2))*6 + cslot];
        if (cint) {
            int rs = (r==0)?0:(r==1)?1:(r==2)?2:(r==510)?3:(r==511)?4:(r==512)?5:-1;
            if (rs >= 0) {
                float s = 0.f;
                #pragma unroll
                for (int ch = 0; ch < 16; ch++)
                    s += ws[WS_BIG + (((size_t)b*16 + ch)*6 + rs)*512 + (c-2)];
                v -= CFLc * s;
            }
        }
        Eout[(size_t)b*SE + (size_t)r*NP + c] = v;
    }
}

// ============ Faraday edges -> scratch (reads E only) ============
__global__ __launch_bounds__(256) void k_faraday_edges(
    const float* __restrict__ E,
    const float* __restrict__ kef, const float* __restrict__ keb,
    float* __restrict__ ws)
{
    int id = blockIdx.x;
    if (id < 2048) {
        // hx edge: one wave per (b, r)
        int b = id >> 7;
        int g = id & 127;
        int lane = threadIdx.x & 63;
        int r = g*4 + (threadIdx.x >> 6);   // 0..510
        if (r > 510) return;
        const float* Eb = E + (size_t)b*SE + (size_t)r*NP;
        float af0=0, af1=0, ab0=0, ab1=0;
        for (int m = lane; m < NP; m += 64) {
            float e0 = Eb[m], e1 = Eb[NP+m], e2 = Eb[2*NP+m];
            if (m <= 511) {
                af0 += e0*kef[m] + e1*kef[512+m] + e2*kef[1024+m];
                ab0 += e0*keb[m] + e1*keb[512+m] + e2*keb[1024+m];
            }
            if (m >= 1) {
                af1 += e0*kef[m-1] + e1*kef[512+m-1] + e2*kef[1024+m-1];
                ab1 += e0*keb[m-1] + e1*keb[512+m-1] + e2*keb[1024+m-1];
            }
        }
        #pragma unroll
        for (int off = 32; off > 0; off >>= 1) {
            af0 += __shfl_down(af0, off); af1 += __shfl_down(af1, off);
            ab0 += __shfl_down(ab0, off); ab1 += __shfl_down(ab1, off);
        }
        if (lane == 0) {
            float* o = ws + WS_SMALL + ((size_t)b*512 + r)*4;
            o[0] = af0; o[1] = af1; o[2] = ab0; o[3] = ab1;
        }
    } else {
        // hy edge: thread per col c, 16 p-chunks of 32
        int t = id - 2048;
        int b = t >> 5;
        int rem = t & 31;
        int chunk = rem >> 1;
        int c = (rem & 1)*256 + threadIdx.x;   // 0..510
        if (c > 510) return;
        int p0 = chunk*32, p1 = p0 + 32;
        const float* Eb = E + (size_t)b*SE;
        float af0=0, af1=0, ab0=0, ab1=0;
        float r0[3], r1[3];
        #pragma unroll
        for (int q = 0; q < 3; q++) r0[q] = Eb[(size_t)p0*NP + c + q];
        for (int p = p0; p < p1; p++) {
            #pragma unroll
            for (int q = 0; q < 3; q++) r1[q] = Eb[(size_t)(p+1)*NP + c + q];
            float cf0 = kef[p], cf1 = kef[512+p], cf2 = kef[1024+p];
            float cb0 = keb[p], cb1 = keb[512+p], cb2 = keb[1024+p];
            af0 += r0[0]*cf0 + r0[1]*cf1 + r0[2]*cf2;
            af1 += r1[0]*cf0 + r1[1]*cf1 + r1[2]*cf2;
            ab0 += r0[0]*cb0 + r0[1]*cb1 + r0[2]*cb2;
            ab1 += r1[0]*cb0 + r1[1]*cb1 + r1[2]*cb2;
            r0[0]=r1[0]; r0[1]=r1[1]; r0[2]=r1[2];
        }
        float* o = ws + WS_BIG + (((size_t)b*16 + chunk)*4)*512 + c;
        o[0*512] = af0; o[1*512] = af1; o[2*512] = ab0; o[3*512] = ab1;
    }
}

// ============ Faraday local: 4-row blocking, writes COMPLETE Hx_out and Hy_out ============
__global__ __launch_bounds__(256) void k_faraday_local(
    const float* __restrict__ E, const float* __restrict__ Hx, const float* __restrict__ Hy,
    const float* __restrict__ beta, const float* __restrict__ delta,
    const float* __restrict__ fb, const float* __restrict__ fd, const float* __restrict__ fy,
    const float* __restrict__ ws,
    float* __restrict__ Hxout, float* __restrict__ Hyout)
{
    __shared__ float gs[12];
    load_g(beta, delta, fb, fd, fy, gs);
    int b = blockIdx.z;
    int y = blockIdx.y;
    const float* Eb = E + (size_t)b*SE;
    if (y < 128) {
        // Hx: rows r0..r0+3 (<=510), cols 0..511
        int c = blockIdx.x*256 + threadIdx.x;
        if (c > 511) return;
        int r0 = y*4;
        int c0 = max(c-1,0), c1 = c, c2 = min(c+1,512), c3 = min(c+2,512);
        float e[6][4];
        #pragma unroll
        for (int k = 0; k < 6; k++) {
            const float* p = Eb + (size_t)min(r0+k,512)*NP;
            e[k][0]=p[c0]; e[k][1]=p[c1]; e[k][2]=p[c2]; e[k][3]=p[c3];
        }
        bool cint = (c >= 1 && c <= 510);
        int slot = (c==0)?0:(c==1)?1:(c==510)?2:(c==511)?3:-1;
        #pragma unroll
        for (int j = 0; j < 4; j++) {
            int r = r0 + j;
            if (r > 510) break;   // uniform
            float v = Hx[(size_t)b*SHX + (size_t)r*NN + c];
            if (cint) {
                float s = 0.f;
                #pragma unroll
                for (int p = 0; p < 3; p++)
                    #pragma unroll
                    for (int q = 0; q < 4; q++) s += gs[p*4+q] * e[j+p][q];
                v -= CFLc * s;
            }
            if (slot >= 0)
                v -= CFLc * ws[WS_SMALL + ((size_t)b*512 + r)*4 + slot];
            Hxout[(size_t)b*SHX + (size_t)r*NN + c] = v;
        }
    } else {
        // Hy: rows r0..r0+3 (<=511), cols 0..510
        int c = blockIdx.x*256 + threadIdx.x;
        if (c > 510) return;
        int r0 = (y-128)*4;
        float e[7][3];
        #pragma unroll
        for (int k = 0; k < 7; k++) {
            const float* p = Eb + (size_t)min(max(r0-1+k,0),512)*NP + c;
            e[k][0]=p[0]; e[k][1]=p[1]; e[k][2]=p[2];
        }
        #pragma unroll
        for (int j = 0; j < 4; j++) {
            int r = r0 + j;   // <=511 always
            float v = Hy[(size_t)b*SHY + (size_t)r*NM + c];
            if (r >= 1 && r <= 510) {
                float s = 0.f;
                #pragma unroll
                for (int p = 0; p < 4; p++)
                    #pragma unroll
                    for (int q = 0; q < 3; q++) s += gs[q*4+p] * e[j+p][q];
                v += CFLc * s;
            }
            int rs = (r==0)?0:(r==1)?1:(r==510)?2:(r==511)?3:-1;   // uniform
            if (rs >= 0) {
                float s = 0.f;
                #pragma unroll
                for (int ch = 0; ch < 16; ch++)
                    s += ws[WS_BIG + (((size_t)b*16 + ch)*4 + rs)*512 + c];
                v += CFLc * s;
            }
            Hyout[(size_t)b*SHY + (size_t)r*NM + c] = v;
        }
    }
}

// ---------------- driver ----------------

static void run_step(const float* Ein, const float* Hxin, const float* Hyin,
                     float* Eout, float* Hxout, float* Hyout, float* ws,
                     const float* beta, const float* delta,
                     const float* fb, const float* fd, const float* fy,
                     const float* kf, const float* kb, const float* fu, const float* fdn,
                     const float* kef, const float* keb, hipStream_t stream)
{
    dim3 blk(256);
    k_amper_edges<<<dim3(2560), blk, 0, stream>>>(Hxin, Hyin, kf, kb, fu, fdn, ws);
    k_amper_local<<<dim3(3, 129, NB), blk, 0, stream>>>(Ein, Hxin, Hyin, beta, delta, fb, fd, fy, ws, Eout);
    k_faraday_edges<<<dim3(2560), blk, 0, stream>>>(Eout, kef, keb, ws);
    k_faraday_local<<<dim3(2, 256, NB), blk, 0, stream>>>(Eout, Hxin, Hyin, beta, delta, fb, fd, fy, ws, Hxout, Hyout);
}

extern "C" void kernel_launch(void* const* d_in, const int* in_sizes, int n_in,
                              void* d_out, int out_size, void* d_ws, size_t ws_size,
                              hipStream_t stream)
{
    const float* E1   = (const float*)d_in[0];
    const float* Hx1  = (const float*)d_in[1];
    const float* Hy1  = (const float*)d_in[2];
    const float* beta = (const float*)d_in[9];
    const float* delta= (const float*)d_in[10];
    const float* fb   = (const float*)d_in[11];
    const float* fd   = (const float*)d_in[12];
    const float* fy   = (const float*)d_in[13];
    const float* kf   = (const float*)d_in[14];
    const float* kb   = (const float*)d_in[15];
    const float* fu   = (const float*)d_in[16];
    const float* fdn  = (const float*)d_in[17];
    const float* kef  = (const float*)d_in[18];
    const float* keb  = (const float*)d_in[19];

    float* out = (float*)d_out;
    float* ws  = (float*)d_ws;   // needs WS_TOT*4 = ~3.34 MB
    size_t SEa = (size_t)NB * SE;
    size_t SHa = (size_t)NB * SHX;   // == NB*SHY
    float* E2  = out;
    float* Hx2 = E2  + SEa;
    float* Hy2 = Hx2 + SHa;
    float* E3  = Hy2 + SHa;
    float* Hx3 = E3  + SEa;
    float* Hy3 = Hx3 + SHa;
    float* E4  = Hy3 + SHa;
    float* Hx4 = E4  + SEa;
    float* Hy4 = Hx4 + SHa;

    run_step(E1, Hx1, Hy1, E2, Hx2, Hy2, ws, beta, delta, fb, fd, fy, kf, kb, fu, fdn, kef, keb, stream);
    run_step(E2, Hx2, Hy2, E3, Hx3, Hy3, ws, beta, delta, fb, fd, fy, kf, kb, fu, fdn, kef, keb, stream);
    run_step(E3, Hx3, Hy3, E4, Hx4, Hy4, ws, beta, delta, fb, fd, fy, kf, kb, fu, fdn, kef, keb, stream);
}